// Round 18
// baseline (3521.856 us; speedup 1.0000x reference)
//
#include <hip/hip_runtime.h>
#include <math.h>

#define BB    256
#define NN_   128
#define ZD    64
#define RD    128
#define HID   256
#define NSTEPS 50
#define NT    16
#define NTILES 8
#define TPB   1024
#define PADD  258   // f64 row stride (516 f32)
#define SPLIT 25    // steps >= SPLIT use f32 decode + f32 drift

// ---------- fast f64-accuracy exp/sigmoid/gelu ----------
__device__ __forceinline__ double fast_exp_d(double x) {
    const double L2E   = 1.44269504088896340736;
    const double LN2HI = 6.93147180369123816490e-01;
    const double LN2LO = 1.90821492927058770002e-10;
    const double MAGIC = 6755399441055744.0;           // 1.5*2^52
    double vn = fma(x, L2E, MAGIC);
    int ni = __double2loint(vn);
    double n = vn - MAGIC;
    double r = fma(n, -LN2HI, x);
    r = fma(n, -LN2LO, r);
    double r2 = r * r;
    double r4 = r2 * r2;
    double p01 = 1.0 + r;
    double p23 = fma(r, 1.66666666666666666667e-01, 0.5);
    double p45 = fma(r, 8.33333333333333333333e-03, 4.16666666666666666667e-02);
    double p67 = fma(r, 1.98412698412698412698e-04, 1.38888888888888888889e-03);
    double p89 = fma(r, 2.75573192239858906526e-06, 2.48015873015873015873e-05);
    double pAB = fma(r, 2.50521083854417187751e-08, 2.75573192239858906526e-07);
    double q0 = fma(r2, p23, p01);
    double q1 = fma(r2, p67, p45);
    double q2 = fma(r2, pAB, p89);
    double p = fma(r4, fma(r4, q2, q1), q0);
    return p * __hiloint2double((1023 + ni) << 20, 0);
}

__device__ __forceinline__ double sigmoid_d(double w) {
    double wc = fmin(fmax(w, -60.0), 60.0);
    double e = fast_exp_d(-wc);
    double d = 1.0 + e;
    float r0 = __builtin_amdgcn_rcpf((float)d);
    double y = (double)r0;
    y = fma(y, fma(-d, y, 1.0), y);
    y = fma(y, fma(-d, y, 1.0), y);
    return y;
}

__device__ __forceinline__ double gelu_d(double x) {
    const double c2 = 1.59576912160573071176;
    double w = c2 * x * fma(0.044715, x * x, 1.0);
    return x * sigmoid_d(w);
}

__device__ __forceinline__ void gelu_both_d(double x, double& h, double& gp) {
    const double c  = 0.79788456080286535588;
    const double a  = 0.044715;
    double x2 = x * x;
    double w  = (2.0 * c) * x * fma(a, x2, 1.0);
    double hp = sigmoid_d(w);
    h = x * hp;
    double s = hp * (1.0 - hp);
    gp = fma(x * s, (2.0 * c) * fma(3.0 * a, x2, 1.0), hp);
}

// f32 gelu: hardware __expf + rcp/1-Newton (rel err ~1e-7)
__device__ __forceinline__ void gelu_both_f(float x, float& h, float& gp) {
    const float c2 = 1.5957691216f;      // 2*sqrt(2/pi)
    float x2 = x * x;
    float w  = c2 * x * fmaf(0.044715f, x2, 1.0f);
    float e  = __expf(-w);
    float d  = 1.0f + e;
    float r0 = __builtin_amdgcn_rcpf(d);
    float hp = r0 * fmaf(-d, r0, 2.0f);  // 1 Newton step
    h = x * hp;
    float sg = hp * (1.0f - hp);
    gp = fmaf(x * sg, c2 * fmaf(0.134145f, x2, 1.0f), hp);
}

__device__ __forceinline__ float gelu_f32(float x) {
    const float c2 = 1.5957691216f;
    float w  = c2 * x * fmaf(0.044715f, x * x, 1.0f);
    float e  = __expf(-w);
    float d  = 1.0f + e;
    float r0 = __builtin_amdgcn_rcpf(d);
    float hp = r0 * fmaf(-d, r0, 2.0f);
    return x * hp;
}

// ---------- dynamic LDS layout (~147 KB) ----------
struct Smem {
    double h_t[NT][PADD];        // decode hidden tile: 16 f64 rows / 32 f32 rows
    float  wd2t_f[8][PADD];      // Wd2^T (f32 exact)
    double z_ds[ZD];
    double hb_ds[HID];           // pooled / drift hidden (f64 path)
    double scratch4[4][HID];     // A-partials / S-partials
    double pmgz[1024];           // zdot parts / mu parts (f64 or 2048 f32) / gzp
    double res_r[NT][8];         // residual tile (f64 16x8 / f32 32x8) / r_d alias
    double bp_d[16][ZD];         // drift-out partials
    double bd2_d[8];
    double bb2_d[ZD];
    double hbt_s[HID];           // step-invariant drift-hidden base
    double wbt_s[HID];           // Wb1 t-row
    float  bd1_s[HID];
    float  x_s[NN_][8];
    float  y_s[NN_][8];
    float  m_s[NN_];
    float  z_f[ZD];              // f32 shadow of z (late-step drift)
    float  hb_f[HID];            // f32 drift hidden (late steps)
    __align__(16) float4 wd1z4[HID][16];   // Wd1 z-block, swizzled
};

// r17 confirmed: 1509 us, absmax 0.1640625, barrier cost ~90ns each.
// r18: software-pipeline the decode tile loop in BOTH step loops:
//   F(0) bar M(0) bar; { R(k) || F(k+1) } bar { B(k) || M(k+1) } bar; ...
// Barriers: Loop A 24->17/step, Loop B 12->9/step. R (idle-heavy) hides
// under F; B's FMAs overlap M's LDS reads. gp registers double-buffered.
// Arithmetic bit-identical to r17 -> absmax must stay exactly 0.1640625.
__global__ void __launch_bounds__(TPB)
nets_sampler_kernel(
    const float* __restrict__ x_ctx, const float* __restrict__ y_ctx,
    const float* __restrict__ mask,  const float* __restrict__ z0,
    const float* __restrict__ noise,
    const float* __restrict__ We1, const float* __restrict__ be1,
    const float* __restrict__ We2, const float* __restrict__ be2,
    const float* __restrict__ Wd1, const float* __restrict__ bd1,
    const float* __restrict__ Wd2, const float* __restrict__ bd2,
    const float* __restrict__ Wb1, const float* __restrict__ bb1,
    const float* __restrict__ Wb2, const float* __restrict__ bb2,
    float* __restrict__ out)
{
    extern __shared__ char smem_raw[];
    Smem& sm = *reinterpret_cast<Smem*>(smem_raw);

    const int b   = blockIdx.x;
    const int tid = threadIdx.x;
    const int j   = tid & 255;       // hidden column
    const int q2  = tid >> 8;        // quarter (0..3)
    const int du_k = tid & 63, du_c = tid >> 6;   // 64x16 partition
    double* r_d = &sm.res_r[0][0];   // alias (pre-loop only)

    // ---------------- loads ----------------
    if (tid < 256) {
        reinterpret_cast<float4*>(&sm.x_s[0][0])[tid] =
            reinterpret_cast<const float4*>(x_ctx + (size_t)b * NN_ * 8)[tid];
        reinterpret_cast<float4*>(&sm.y_s[0][0])[tid] =
            reinterpret_cast<const float4*>(y_ctx + (size_t)b * NN_ * 8)[tid];
        sm.bd1_s[j] = bd1[j];
        float4 a0 = reinterpret_cast<const float4*>(Wd2 + (size_t)j * 8)[0];
        float4 a1 = reinterpret_cast<const float4*>(Wd2 + (size_t)j * 8)[1];
        sm.wd2t_f[0][j] = a0.x; sm.wd2t_f[1][j] = a0.y;
        sm.wd2t_f[2][j] = a0.z; sm.wd2t_f[3][j] = a0.w;
        sm.wd2t_f[4][j] = a1.x; sm.wd2t_f[5][j] = a1.y;
        sm.wd2t_f[6][j] = a1.z; sm.wd2t_f[7][j] = a1.w;
    }
    if (tid < NN_) sm.m_s[tid] = mask[(size_t)b * NN_ + tid];
    if (tid < ZD) {
        float zf = z0[(size_t)b * ZD + tid];
        sm.z_ds[tid]  = (double)zf;
        sm.z_f[tid]   = zf;
        sm.bb2_d[tid] = (double)bb2[tid];
    }
    if (tid < 8) sm.bd2_d[tid] = (double)bd2[tid];

    // Wd1 z-block -> swizzled LDS
#pragma unroll
    for (int kk = 0; kk < 16; kk++) {
        const int k = q2 * 16 + kk;
        const float v = Wd1[(8 + k) * HID + j];
        reinterpret_cast<float*>(&sm.wd1z4[j][0])[4 * ((k >> 2) ^ (j & 15)) + (k & 3)] = v;
    }

    float wd1x[8];                       // Wd1 x-rows, column j (exact f32)
#pragma unroll
    for (int k = 0; k < 8; k++) wd1x[k] = Wd1[k * HID + j];

    __syncthreads();

    // ---------------- encoder (once, f64) ----------------
    if (tid < 256) {
        float we1r[16];
#pragma unroll
        for (int k = 0; k < 16; k++) we1r[k] = We1[k * HID + j];
        double be1_d = (double)be1[j];
        double msum = 0.0;
        for (int n = 0; n < NN_; n++) msum += (double)sm.m_s[n];
        msum = fmax(msum, 1.0);
        double pacc = 0.0;
        for (int n = 0; n < NN_; n++) {
            double pre = be1_d;
#pragma unroll
            for (int k = 0; k < 8; k++) pre = fma((double)sm.x_s[n][k], (double)we1r[k], pre);
#pragma unroll
            for (int k = 0; k < 8; k++) pre = fma((double)sm.y_s[n][k], (double)we1r[8 + k], pre);
            pacc += gelu_d(pre) * (double)sm.m_s[n];
        }
        sm.hb_ds[j] = pacc / msum;
    }
    __syncthreads();
    if (tid < 256) {
        int i = tid & 127, half = tid >> 7;
        double racc = 0.0;
        for (int jj = half * 128; jj < half * 128 + 128; jj++)
            racc = fma(sm.hb_ds[jj], (double)We2[jj * RD + i], racc);
        sm.scratch4[half][i] = racc;
    }
    __syncthreads();
    if (tid < RD) r_d[tid] = sm.scratch4[0][tid] + sm.scratch4[1][tid] + (double)be2[tid];
    __syncthreads();

    if (tid < 256) {                     // step-invariant drift-hidden -> LDS
        double hbr = (double)bb1[j];
        for (int k = 0; k < RD; k++)
            hbr = fma(r_d[k], (double)Wb1[(ZD + k) * HID + j], hbr);
        sm.hbt_s[j] = hbr;
        sm.wbt_s[j] = (double)Wb1[(ZD + RD) * HID + j];
    }
    __syncthreads();                     // r_d alias free after this

    const double dt  = 1.0 / (double)NSTEPS;
    const double nsc = sqrt(2.0 * 1.0 * dt);

    float* h_f   = reinterpret_cast<float*>(&sm.h_t[0][0]);    // f32 alias, stride PADD
    float* res_f = reinterpret_cast<float*>(&sm.res_r[0][0]);  // f32 alias (256 slots)
    float* pm_f  = reinterpret_cast<float*>(&sm.pmgz[0]);      // f32 alias (2048 slots)

    // ================= LOOP A: steps 0..SPLIT-1, pure f64 =================
    for (int s = 0; s < SPLIT; s++) {
        const double t = (double)s * dt;

        float nzf = 0.0f;
        if (tid < ZD) nzf = noise[((size_t)s * BB + b) * ZD + tid];

        // phase 1: A drift-hidden partials (f64) + zdot quarter-partials
        {
            const int kb = q2 * 16;
            const float* wb1p = Wb1 + kb * HID + j;
            double a0 = 0.0;
#pragma unroll 8
            for (int kk = 0; kk < 16; kk++)
                a0 = fma(sm.z_ds[kb + kk], (double)wb1p[kk * HID], a0);
            sm.scratch4[q2][j] = a0;

            double zq0 = 0.0, zq1 = 0.0;
#pragma unroll
            for (int q = q2 * 4; q < q2 * 4 + 4; q++) {
                float4 wv = sm.wd1z4[j][q ^ (j & 15)];
                const int k = q * 4;
                zq0 = fma(sm.z_ds[k],     (double)wv.x, zq0);
                zq1 = fma(sm.z_ds[k + 1], (double)wv.y, zq1);
                zq0 = fma(sm.z_ds[k + 2], (double)wv.z, zq0);
                zq1 = fma(sm.z_ds[k + 3], (double)wv.w, zq1);
            }
            sm.pmgz[q2 * 256 + j] = zq0 + zq1;
        }
        __syncthreads();
        // phase 2: drift hidden gelu (f64)
        if (tid < 256) {
            double hacc = sm.hbt_s[j] + t * sm.wbt_s[j]
                        + sm.scratch4[0][j] + sm.scratch4[1][j]
                        + sm.scratch4[2][j] + sm.scratch4[3][j];
            sm.hb_ds[j] = gelu_d(hacc);
        }
        __syncthreads();
        // drift out partials (f64; no trailing barrier)
        {
            const float* wb2p = Wb2 + (du_c * 16) * ZD + du_k;
            double acc = 0.0;
#pragma unroll 8
            for (int i = 0; i < 16; i++)
                acc = fma(sm.hb_ds[du_c * 16 + i], (double)wb2p[i * ZD], acc);
            sm.bp_d[du_c][du_k] = acc;
        }

        if (s > 0) {
            const double zpre = (double)sm.bd1_s[j]
                + ((sm.pmgz[j] + sm.pmgz[256 + j]) + (sm.pmgz[512 + j] + sm.pmgz[768 + j]));
            const int rb = q2 * 4;

            float c0, c1, c2, c3;          // gp for current tile
            float n0, n1, n2, n3;          // gp for next tile
            double T0 = 0.0, T1 = 0.0, T2 = 0.0, T3 = 0.0;
            double T4 = 0.0, T5 = 0.0, T6 = 0.0, T7 = 0.0;

#define FA(TI, G0, G1, G2, G3) { \
            const int xb = (TI) * NT + rb; \
            { \
                const float4 xa = *reinterpret_cast<const float4*>(&sm.x_s[xb + 0][0]); \
                const float4 xbv = *reinterpret_cast<const float4*>(&sm.x_s[xb + 0][4]); \
                const float4 xc = *reinterpret_cast<const float4*>(&sm.x_s[xb + 1][0]); \
                const float4 xdv = *reinterpret_cast<const float4*>(&sm.x_s[xb + 1][4]); \
                double p0 = zpre, p1 = zpre; \
                p0 = fma((double)xa.x, (double)wd1x[0], p0); \
                p0 = fma((double)xa.y, (double)wd1x[1], p0); \
                p0 = fma((double)xa.z, (double)wd1x[2], p0); \
                p0 = fma((double)xa.w, (double)wd1x[3], p0); \
                p0 = fma((double)xbv.x, (double)wd1x[4], p0); \
                p0 = fma((double)xbv.y, (double)wd1x[5], p0); \
                p0 = fma((double)xbv.z, (double)wd1x[6], p0); \
                p0 = fma((double)xbv.w, (double)wd1x[7], p0); \
                p1 = fma((double)xc.x, (double)wd1x[0], p1); \
                p1 = fma((double)xc.y, (double)wd1x[1], p1); \
                p1 = fma((double)xc.z, (double)wd1x[2], p1); \
                p1 = fma((double)xc.w, (double)wd1x[3], p1); \
                p1 = fma((double)xdv.x, (double)wd1x[4], p1); \
                p1 = fma((double)xdv.y, (double)wd1x[5], p1); \
                p1 = fma((double)xdv.z, (double)wd1x[6], p1); \
                p1 = fma((double)xdv.w, (double)wd1x[7], p1); \
                double h0, g0, h1, g1; \
                gelu_both_d(p0, h0, g0); \
                gelu_both_d(p1, h1, g1); \
                sm.h_t[rb + 0][j] = h0; G0 = (float)g0; \
                sm.h_t[rb + 1][j] = h1; G1 = (float)g1; \
            } \
            { \
                const float4 xa = *reinterpret_cast<const float4*>(&sm.x_s[xb + 2][0]); \
                const float4 xbv = *reinterpret_cast<const float4*>(&sm.x_s[xb + 2][4]); \
                const float4 xc = *reinterpret_cast<const float4*>(&sm.x_s[xb + 3][0]); \
                const float4 xdv = *reinterpret_cast<const float4*>(&sm.x_s[xb + 3][4]); \
                double p0 = zpre, p1 = zpre; \
                p0 = fma((double)xa.x, (double)wd1x[0], p0); \
                p0 = fma((double)xa.y, (double)wd1x[1], p0); \
                p0 = fma((double)xa.z, (double)wd1x[2], p0); \
                p0 = fma((double)xa.w, (double)wd1x[3], p0); \
                p0 = fma((double)xbv.x, (double)wd1x[4], p0); \
                p0 = fma((double)xbv.y, (double)wd1x[5], p0); \
                p0 = fma((double)xbv.z, (double)wd1x[6], p0); \
                p0 = fma((double)xbv.w, (double)wd1x[7], p0); \
                p1 = fma((double)xc.x, (double)wd1x[0], p1); \
                p1 = fma((double)xc.y, (double)wd1x[1], p1); \
                p1 = fma((double)xc.z, (double)wd1x[2], p1); \
                p1 = fma((double)xc.w, (double)wd1x[3], p1); \
                p1 = fma((double)xdv.x, (double)wd1x[4], p1); \
                p1 = fma((double)xdv.y, (double)wd1x[5], p1); \
                p1 = fma((double)xdv.z, (double)wd1x[6], p1); \
                p1 = fma((double)xdv.w, (double)wd1x[7], p1); \
                double h0, g0, h1, g1; \
                gelu_both_d(p0, h0, g0); \
                gelu_both_d(p1, h1, g1); \
                sm.h_t[rb + 2][j] = h0; G2 = (float)g0; \
                sm.h_t[rb + 3][j] = h1; G3 = (float)g1; \
            } }

#define MA() { \
            const int q = tid >> 7, pair = tid & 127; \
            const int nn = pair >> 3, yd = pair & 7; \
            const double2* hrow = reinterpret_cast<const double2*>(&sm.h_t[nn][q * 32]); \
            const float2*  wrow = reinterpret_cast<const float2*>(&sm.wd2t_f[yd][q * 32]); \
            double a0 = 0.0, a1 = 0.0; \
            _Pragma("unroll 8") \
            for (int i = 0; i < 16; i++) { \
                double2 hv = hrow[i]; \
                float2  wv = wrow[i]; \
                a0 = fma(hv.x, (double)wv.x, a0); \
                a1 = fma(hv.y, (double)wv.y, a1); \
            } \
            sm.pmgz[q * 128 + pair] = a0 + a1; }

#define RA(TI) if (tid < 128) { \
            const int nn = tid >> 3, yd = tid & 7; \
            double mu = sm.bd2_d[yd]; \
            _Pragma("unroll") \
            for (int q = 0; q < 8; q++) mu += sm.pmgz[q * 128 + tid]; \
            sm.res_r[nn][yd] = 4.0 * t * (mu - (double)sm.y_s[(TI) * NT + nn][yd]) \
                                       * (double)sm.m_s[(TI) * NT + nn]; }

#define BA(G0, G1, G2, G3) { \
            const double2* rr0 = reinterpret_cast<const double2*>(&sm.res_r[rb + 0][0]); \
            const double2* rr1 = reinterpret_cast<const double2*>(&sm.res_r[rb + 1][0]); \
            const double2* rr2 = reinterpret_cast<const double2*>(&sm.res_r[rb + 2][0]); \
            const double2* rr3 = reinterpret_cast<const double2*>(&sm.res_r[rb + 3][0]); \
            double2 a0, a1, a2, a3; \
            double g; \
            g = (double)G0; \
            a0 = rr0[0]; a1 = rr0[1]; a2 = rr0[2]; a3 = rr0[3]; \
            T0 = fma(a0.x, g, T0); T1 = fma(a0.y, g, T1); \
            T2 = fma(a1.x, g, T2); T3 = fma(a1.y, g, T3); \
            T4 = fma(a2.x, g, T4); T5 = fma(a2.y, g, T5); \
            T6 = fma(a3.x, g, T6); T7 = fma(a3.y, g, T7); \
            g = (double)G1; \
            a0 = rr1[0]; a1 = rr1[1]; a2 = rr1[2]; a3 = rr1[3]; \
            T0 = fma(a0.x, g, T0); T1 = fma(a0.y, g, T1); \
            T2 = fma(a1.x, g, T2); T3 = fma(a1.y, g, T3); \
            T4 = fma(a2.x, g, T4); T5 = fma(a2.y, g, T5); \
            T6 = fma(a3.x, g, T6); T7 = fma(a3.y, g, T7); \
            g = (double)G2; \
            a0 = rr2[0]; a1 = rr2[1]; a2 = rr2[2]; a3 = rr2[3]; \
            T0 = fma(a0.x, g, T0); T1 = fma(a0.y, g, T1); \
            T2 = fma(a1.x, g, T2); T3 = fma(a1.y, g, T3); \
            T4 = fma(a2.x, g, T4); T5 = fma(a2.y, g, T5); \
            T6 = fma(a3.x, g, T6); T7 = fma(a3.y, g, T7); \
            g = (double)G3; \
            a0 = rr3[0]; a1 = rr3[1]; a2 = rr3[2]; a3 = rr3[3]; \
            T0 = fma(a0.x, g, T0); T1 = fma(a0.y, g, T1); \
            T2 = fma(a1.x, g, T2); T3 = fma(a1.y, g, T3); \
            T4 = fma(a2.x, g, T4); T5 = fma(a2.y, g, T5); \
            T6 = fma(a3.x, g, T6); T7 = fma(a3.y, g, T7); }

            // pipelined: F(0) bar M(0) bar; {R(k)||F(k+1)} bar {B(k)||M(k+1)} bar
            FA(0, c0, c1, c2, c3)
            __syncthreads();
            MA()
            __syncthreads();
            for (int k = 0; k < NTILES - 1; k++) {
                RA(k)
                FA(k + 1, n0, n1, n2, n3)
                __syncthreads();
                BA(c0, c1, c2, c3)
                MA()
                __syncthreads();
                c0 = n0; c1 = n1; c2 = n2; c3 = n3;
            }
            RA(NTILES - 1)
            __syncthreads();
            BA(c0, c1, c2, c3)
#undef FA
#undef MA
#undef RA
#undef BA
            {
                double S = T0 * (double)sm.wd2t_f[0][j];
                S = fma(T1, (double)sm.wd2t_f[1][j], S);
                S = fma(T2, (double)sm.wd2t_f[2][j], S);
                S = fma(T3, (double)sm.wd2t_f[3][j], S);
                S = fma(T4, (double)sm.wd2t_f[4][j], S);
                S = fma(T5, (double)sm.wd2t_f[5][j], S);
                S = fma(T6, (double)sm.wd2t_f[6][j], S);
                S = fma(T7, (double)sm.wd2t_f[7][j], S);
                sm.scratch4[q2][j] = S;
            }
            __syncthreads();
            // gradient matvec (f64)
            {
                const int k = du_k, c = du_c;
                const int qk = k >> 2, ck = k & 3;
                double acc = 0.0;
#pragma unroll 8
                for (int i = 0; i < 16; i++) {
                    const int jj = c * 16 + i;
                    const float w = reinterpret_cast<const float*>(&sm.wd1z4[jj][0])
                                        [4 * (qk ^ (jj & 15)) + ck];
                    const double sv = sm.scratch4[0][jj] + sm.scratch4[1][jj]
                                    + sm.scratch4[2][jj] + sm.scratch4[3][jj];
                    acc = fma(sv, (double)w, acc);
                }
                sm.pmgz[c * 64 + k] = acc;
            }
            __syncthreads();
        } else {
            __syncthreads();   // s==0: make bp_d visible to the update
        }

        // z update
        if (tid < ZD) {
            double gsum = sm.z_ds[tid];
            if (s > 0) {
#pragma unroll
                for (int c = 0; c < 16; c++) gsum += sm.pmgz[c * 64 + tid];
            }
            gsum = fmin(fmax(gsum, -100.0), 100.0);
            double bdr = sm.bb2_d[tid];
#pragma unroll
            for (int c = 0; c < 16; c++) bdr += sm.bp_d[c][tid];
            double znew = sm.z_ds[tid] + (bdr - gsum) * dt + nsc * (double)nzf;
            sm.z_ds[tid] = znew;
            sm.z_f[tid]  = (float)znew;
        }
        __syncthreads();
    }

    // ========== LOOP B: steps SPLIT..NSTEPS-1, f32, 32-row tiles ==========
    for (int s = SPLIT; s < NSTEPS; s++) {
        const double t = (double)s * dt;

        float nzf = 0.0f;
        if (tid < ZD) nzf = noise[((size_t)s * BB + b) * ZD + tid];

        // phase 1: A drift-hidden partials (f32) + zdot quarter-partials (f64)
        {
            const int kb = q2 * 16;
            const float* wb1p = Wb1 + kb * HID + j;
            float a0f = 0.0f;
#pragma unroll 8
            for (int kk = 0; kk < 16; kk++)
                a0f = fmaf(sm.z_f[kb + kk], wb1p[kk * HID], a0f);
            sm.scratch4[q2][j] = (double)a0f;

            double zq0 = 0.0, zq1 = 0.0;
#pragma unroll
            for (int q = q2 * 4; q < q2 * 4 + 4; q++) {
                float4 wv = sm.wd1z4[j][q ^ (j & 15)];
                const int k = q * 4;
                zq0 = fma(sm.z_ds[k],     (double)wv.x, zq0);
                zq1 = fma(sm.z_ds[k + 1], (double)wv.y, zq1);
                zq0 = fma(sm.z_ds[k + 2], (double)wv.z, zq0);
                zq1 = fma(sm.z_ds[k + 3], (double)wv.w, zq1);
            }
            sm.pmgz[q2 * 256 + j] = zq0 + zq1;
        }
        __syncthreads();
        // phase 2: drift hidden gelu (f32)
        if (tid < 256) {
            double hacc = sm.hbt_s[j] + t * sm.wbt_s[j]
                        + sm.scratch4[0][j] + sm.scratch4[1][j]
                        + sm.scratch4[2][j] + sm.scratch4[3][j];
            sm.hb_f[j] = gelu_f32((float)hacc);
        }
        __syncthreads();
        // drift out partials (f32)
        {
            const float* wb2p = Wb2 + (du_c * 16) * ZD + du_k;
            float accf = 0.0f;
#pragma unroll 8
            for (int i = 0; i < 16; i++)
                accf = fmaf(sm.hb_f[du_c * 16 + i], wb2p[i * ZD], accf);
            sm.bp_d[du_c][du_k] = (double)accf;
        }

        const double zpre = (double)sm.bd1_s[j]
            + ((sm.pmgz[j] + sm.pmgz[256 + j]) + (sm.pmgz[512 + j] + sm.pmgz[768 + j]));
        const float zpre_f = (float)zpre;
        const int rb2 = q2 * 8;          // 8 rows/thread within a 32-row tile

        float cA, cB, cC, cD, cE, cF, cG, cH;   // current tile gp
        float nA, nB, nC, nD, nE, nF, nG, nH;   // next tile gp
        float T0 = 0.f, T1 = 0.f, T2 = 0.f, T3 = 0.f;
        float T4 = 0.f, T5 = 0.f, T6 = 0.f, T7 = 0.f;

#define FPAIR(XB, RO, GA, GB) { \
        const float4 xa = *reinterpret_cast<const float4*>(&sm.x_s[(XB) + (RO)][0]); \
        const float4 xbv = *reinterpret_cast<const float4*>(&sm.x_s[(XB) + (RO)][4]); \
        const float4 xc = *reinterpret_cast<const float4*>(&sm.x_s[(XB) + (RO) + 1][0]); \
        const float4 xdv = *reinterpret_cast<const float4*>(&sm.x_s[(XB) + (RO) + 1][4]); \
        float p0 = zpre_f, p1 = zpre_f; \
        p0 = fmaf(xa.x, wd1x[0], p0);  p0 = fmaf(xa.y, wd1x[1], p0); \
        p0 = fmaf(xa.z, wd1x[2], p0);  p0 = fmaf(xa.w, wd1x[3], p0); \
        p0 = fmaf(xbv.x, wd1x[4], p0); p0 = fmaf(xbv.y, wd1x[5], p0); \
        p0 = fmaf(xbv.z, wd1x[6], p0); p0 = fmaf(xbv.w, wd1x[7], p0); \
        p1 = fmaf(xc.x, wd1x[0], p1);  p1 = fmaf(xc.y, wd1x[1], p1); \
        p1 = fmaf(xc.z, wd1x[2], p1);  p1 = fmaf(xc.w, wd1x[3], p1); \
        p1 = fmaf(xdv.x, wd1x[4], p1); p1 = fmaf(xdv.y, wd1x[5], p1); \
        p1 = fmaf(xdv.z, wd1x[6], p1); p1 = fmaf(xdv.w, wd1x[7], p1); \
        float h0, g0, h1, g1; \
        gelu_both_f(p0, h0, g0); \
        gelu_both_f(p1, h1, g1); \
        h_f[(rb2 + (RO)) * PADD + j]     = h0; \
        h_f[(rb2 + (RO) + 1) * PADD + j] = h1; \
        GA = g0; GB = g1; }

#define FB(TI, GA, GB, GC, GD, GE, GF, GG, GH) { \
        const int xb = (TI) * 32 + rb2; \
        FPAIR(xb, 0, GA, GB) \
        FPAIR(xb, 2, GC, GD) \
        FPAIR(xb, 4, GE, GF) \
        FPAIR(xb, 6, GG, GH) }

#define MB() { \
        _Pragma("unroll") \
        for (int it = 0; it < 2; it++) { \
            const int slot = tid + it * 1024; \
            const int q = slot >> 8, pair = slot & 255; \
            const int nn = pair >> 3, yd = pair & 7; \
            const float2* hrow = \
                reinterpret_cast<const float2*>(h_f + nn * PADD) + q * 16; \
            const float2* wrow = \
                reinterpret_cast<const float2*>(&sm.wd2t_f[yd][0]) + q * 16; \
            float a0 = 0.f, a1 = 0.f; \
            _Pragma("unroll 8") \
            for (int i = 0; i < 16; i++) { \
                float2 hv = hrow[i]; \
                float2 wv = wrow[i]; \
                a0 = fmaf(hv.x, wv.x, a0); \
                a1 = fmaf(hv.y, wv.y, a1); \
            } \
            pm_f[slot] = a0 + a1; \
        } }

#define RB(TI) if (tid < 256) { \
        const int nn = tid >> 3, yd = tid & 7; \
        double mu = sm.bd2_d[yd]; \
        _Pragma("unroll") \
        for (int q = 0; q < 8; q++) mu += (double)pm_f[q * 256 + tid]; \
        const int row = (TI) * 32 + nn; \
        res_f[tid] = (float)(4.0 * t * (mu - (double)sm.y_s[row][yd]) \
                                     * (double)sm.m_s[row]); }

#define BROW(RO, G) { \
        const float2* rr = reinterpret_cast<const float2*>(res_f + (rb2 + (RO)) * 8); \
        float2 a0 = rr[0], a1 = rr[1], a2 = rr[2], a3 = rr[3]; \
        T0 = fmaf(a0.x, (G), T0); T1 = fmaf(a0.y, (G), T1); \
        T2 = fmaf(a1.x, (G), T2); T3 = fmaf(a1.y, (G), T3); \
        T4 = fmaf(a2.x, (G), T4); T5 = fmaf(a2.y, (G), T5); \
        T6 = fmaf(a3.x, (G), T6); T7 = fmaf(a3.y, (G), T7); }

#define BBLK(GA, GB, GC, GD, GE, GF, GG, GH) { \
        BROW(0, GA) BROW(1, GB) BROW(2, GC) BROW(3, GD) \
        BROW(4, GE) BROW(5, GF) BROW(6, GG) BROW(7, GH) }

        // pipelined: F(0) bar M(0) bar; {R(k)||F(k+1)} bar {B(k)||M(k+1)} bar
        FB(0, cA, cB, cC, cD, cE, cF, cG, cH)
        __syncthreads();
        MB()
        __syncthreads();
        for (int k = 0; k < 3; k++) {
            RB(k)
            FB(k + 1, nA, nB, nC, nD, nE, nF, nG, nH)
            __syncthreads();
            BBLK(cA, cB, cC, cD, cE, cF, cG, cH)
            MB()
            __syncthreads();
            cA = nA; cB = nB; cC = nC; cD = nD;
            cE = nE; cF = nF; cG = nG; cH = nH;
        }
        RB(3)
        __syncthreads();
        BBLK(cA, cB, cC, cD, cE, cF, cG, cH)
#undef FPAIR
#undef FB
#undef MB
#undef RB
#undef BROW
#undef BBLK
        {
            float Sf = T0 * sm.wd2t_f[0][j];
            Sf = fmaf(T1, sm.wd2t_f[1][j], Sf);
            Sf = fmaf(T2, sm.wd2t_f[2][j], Sf);
            Sf = fmaf(T3, sm.wd2t_f[3][j], Sf);
            Sf = fmaf(T4, sm.wd2t_f[4][j], Sf);
            Sf = fmaf(T5, sm.wd2t_f[5][j], Sf);
            Sf = fmaf(T6, sm.wd2t_f[6][j], Sf);
            Sf = fmaf(T7, sm.wd2t_f[7][j], Sf);
            sm.scratch4[q2][j] = (double)Sf;
        }
        __syncthreads();

        // gradient matvec (f64)
        {
            const int k = du_k, c = du_c;
            const int qk = k >> 2, ck = k & 3;
            double acc = 0.0;
#pragma unroll 8
            for (int i = 0; i < 16; i++) {
                const int jj = c * 16 + i;
                const float w = reinterpret_cast<const float*>(&sm.wd1z4[jj][0])
                                    [4 * (qk ^ (jj & 15)) + ck];
                const double sv = sm.scratch4[0][jj] + sm.scratch4[1][jj]
                                + sm.scratch4[2][jj] + sm.scratch4[3][jj];
                acc = fma(sv, (double)w, acc);
            }
            sm.pmgz[c * 64 + k] = acc;
        }
        __syncthreads();
        // z update
        if (tid < ZD) {
            double gsum = sm.z_ds[tid];
#pragma unroll
            for (int c = 0; c < 16; c++) gsum += sm.pmgz[c * 64 + tid];
            gsum = fmin(fmax(gsum, -100.0), 100.0);
            double bdr = sm.bb2_d[tid];
#pragma unroll
            for (int c = 0; c < 16; c++) bdr += sm.bp_d[c][tid];
            double znew = sm.z_ds[tid] + (bdr - gsum) * dt + nsc * (double)nzf;
            sm.z_ds[tid] = znew;
            sm.z_f[tid]  = (float)znew;
        }
        __syncthreads();
    }

    if (tid < ZD) out[(size_t)b * ZD + tid] = (float)sm.z_ds[tid];
}

extern "C" void kernel_launch(void* const* d_in, const int* in_sizes, int n_in,
                              void* d_out, int out_size, void* d_ws, size_t ws_size,
                              hipStream_t stream) {
    const float* x_ctx = (const float*)d_in[0];
    const float* y_ctx = (const float*)d_in[1];
    const float* maskp = (const float*)d_in[2];
    const float* z0    = (const float*)d_in[3];
    const float* noise = (const float*)d_in[4];
    const float* We1   = (const float*)d_in[5];
    const float* be1   = (const float*)d_in[6];
    const float* We2   = (const float*)d_in[7];
    const float* be2   = (const float*)d_in[8];
    const float* Wd1   = (const float*)d_in[9];
    const float* bd1   = (const float*)d_in[10];
    const float* Wd2   = (const float*)d_in[11];
    const float* bd2   = (const float*)d_in[12];
    const float* Wb1   = (const float*)d_in[13];
    const float* bb1   = (const float*)d_in[14];
    const float* Wb2   = (const float*)d_in[15];
    const float* bb2   = (const float*)d_in[16];
    float* out = (float*)d_out;

    (void)hipFuncSetAttribute((const void*)nets_sampler_kernel,
                              hipFuncAttributeMaxDynamicSharedMemorySize,
                              (int)sizeof(Smem));

    nets_sampler_kernel<<<BB, TPB, sizeof(Smem), stream>>>(
        x_ctx, y_ctx, maskp, z0, noise,
        We1, be1, We2, be2, Wd1, bd1, Wd2, bd2, Wb1, bb1, Wb2, bb2, out);
}

// Round 19
// 1507.377 us; speedup vs baseline: 2.3364x; 2.3364x over previous
//
#include <hip/hip_runtime.h>
#include <math.h>

#define BB    256
#define NN_   128
#define ZD    64
#define RD    128
#define HID   256
#define NSTEPS 50
#define NT    16
#define NTILES 8
#define TPB   1024
#define PADD  258   // f64 row stride (516 f32)
#define SPLIT 25    // steps >= SPLIT use f32 decode + f32 drift

// ---------- fast f64-accuracy exp/sigmoid/gelu ----------
__device__ __forceinline__ double fast_exp_d(double x) {
    const double L2E   = 1.44269504088896340736;
    const double LN2HI = 6.93147180369123816490e-01;
    const double LN2LO = 1.90821492927058770002e-10;
    const double MAGIC = 6755399441055744.0;           // 1.5*2^52
    double vn = fma(x, L2E, MAGIC);
    int ni = __double2loint(vn);
    double n = vn - MAGIC;
    double r = fma(n, -LN2HI, x);
    r = fma(n, -LN2LO, r);
    double r2 = r * r;
    double r4 = r2 * r2;
    double p01 = 1.0 + r;
    double p23 = fma(r, 1.66666666666666666667e-01, 0.5);
    double p45 = fma(r, 8.33333333333333333333e-03, 4.16666666666666666667e-02);
    double p67 = fma(r, 1.98412698412698412698e-04, 1.38888888888888888889e-03);
    double p89 = fma(r, 2.75573192239858906526e-06, 2.48015873015873015873e-05);
    double pAB = fma(r, 2.50521083854417187751e-08, 2.75573192239858906526e-07);
    double q0 = fma(r2, p23, p01);
    double q1 = fma(r2, p67, p45);
    double q2 = fma(r2, pAB, p89);
    double p = fma(r4, fma(r4, q2, q1), q0);
    return p * __hiloint2double((1023 + ni) << 20, 0);
}

__device__ __forceinline__ double sigmoid_d(double w) {
    double wc = fmin(fmax(w, -60.0), 60.0);
    double e = fast_exp_d(-wc);
    double d = 1.0 + e;
    float r0 = __builtin_amdgcn_rcpf((float)d);
    double y = (double)r0;
    y = fma(y, fma(-d, y, 1.0), y);
    y = fma(y, fma(-d, y, 1.0), y);
    return y;
}

__device__ __forceinline__ double gelu_d(double x) {
    const double c2 = 1.59576912160573071176;
    double w = c2 * x * fma(0.044715, x * x, 1.0);
    return x * sigmoid_d(w);
}

__device__ __forceinline__ void gelu_both_d(double x, double& h, double& gp) {
    const double c  = 0.79788456080286535588;
    const double a  = 0.044715;
    double x2 = x * x;
    double w  = (2.0 * c) * x * fma(a, x2, 1.0);
    double hp = sigmoid_d(w);
    h = x * hp;
    double s = hp * (1.0 - hp);
    gp = fma(x * s, (2.0 * c) * fma(3.0 * a, x2, 1.0), hp);
}

// f32 gelu: hardware __expf + rcp/1-Newton (rel err ~1e-7)
__device__ __forceinline__ void gelu_both_f(float x, float& h, float& gp) {
    const float c2 = 1.5957691216f;      // 2*sqrt(2/pi)
    float x2 = x * x;
    float w  = c2 * x * fmaf(0.044715f, x2, 1.0f);
    float e  = __expf(-w);
    float d  = 1.0f + e;
    float r0 = __builtin_amdgcn_rcpf(d);
    float hp = r0 * fmaf(-d, r0, 2.0f);  // 1 Newton step
    h = x * hp;
    float sg = hp * (1.0f - hp);
    gp = fmaf(x * sg, c2 * fmaf(0.134145f, x2, 1.0f), hp);
}

__device__ __forceinline__ float gelu_f32(float x) {
    const float c2 = 1.5957691216f;
    float w  = c2 * x * fmaf(0.044715f, x * x, 1.0f);
    float e  = __expf(-w);
    float d  = 1.0f + e;
    float r0 = __builtin_amdgcn_rcpf(d);
    float hp = r0 * fmaf(-d, r0, 2.0f);
    return x * hp;
}

// ---------- dynamic LDS layout (~147 KB) ----------
struct Smem {
    double h_t[NT][PADD];        // decode hidden tile: 16 f64 rows / 32 f32 rows
    float  wd2t_f[8][PADD];      // Wd2^T (f32 exact)
    double z_ds[ZD];
    double hb_ds[HID];           // pooled / drift hidden (f64 path)
    double scratch4[4][HID];     // A-partials / S-partials
    double pmgz[1024];           // zdot parts / mu parts (f64 or 2048 f32) / gzp
    double res_r[NT][8];         // residual tile (f64 16x8 / f32 32x8) / r_d alias
    double bp_d[16][ZD];         // drift-out partials
    double bd2_d[8];
    double bb2_d[ZD];
    double hbt_s[HID];           // step-invariant drift-hidden base
    double wbt_s[HID];           // Wb1 t-row
    float  bd1_s[HID];
    float  x_s[NN_][8];
    float  y_s[NN_][8];
    float  m_s[NN_];
    float  z_f[ZD];              // f32 shadow of z (late-step drift)
    float  hb_f[HID];            // f32 drift hidden (late steps)
    __align__(16) float4 wd1z4[HID][16];   // Wd1 z-block, swizzled
};

// r18 lesson: software-pipelining the tile loop kept F-results + gp
// double-buffers live ACROSS barriers -> 10.9 GB scratch traffic (dur 2.3x).
// Third confirmation that cross-barrier register liveness spills on this
// kernel. REVERT to r17 verbatim (measured best: 1509 us, absmax 0.1640625).
__global__ void __launch_bounds__(TPB)
nets_sampler_kernel(
    const float* __restrict__ x_ctx, const float* __restrict__ y_ctx,
    const float* __restrict__ mask,  const float* __restrict__ z0,
    const float* __restrict__ noise,
    const float* __restrict__ We1, const float* __restrict__ be1,
    const float* __restrict__ We2, const float* __restrict__ be2,
    const float* __restrict__ Wd1, const float* __restrict__ bd1,
    const float* __restrict__ Wd2, const float* __restrict__ bd2,
    const float* __restrict__ Wb1, const float* __restrict__ bb1,
    const float* __restrict__ Wb2, const float* __restrict__ bb2,
    float* __restrict__ out)
{
    extern __shared__ char smem_raw[];
    Smem& sm = *reinterpret_cast<Smem*>(smem_raw);

    const int b   = blockIdx.x;
    const int tid = threadIdx.x;
    const int j   = tid & 255;       // hidden column
    const int q2  = tid >> 8;        // quarter (0..3)
    const int du_k = tid & 63, du_c = tid >> 6;   // 64x16 partition
    double* r_d = &sm.res_r[0][0];   // alias (pre-loop only)

    // ---------------- loads ----------------
    if (tid < 256) {
        reinterpret_cast<float4*>(&sm.x_s[0][0])[tid] =
            reinterpret_cast<const float4*>(x_ctx + (size_t)b * NN_ * 8)[tid];
        reinterpret_cast<float4*>(&sm.y_s[0][0])[tid] =
            reinterpret_cast<const float4*>(y_ctx + (size_t)b * NN_ * 8)[tid];
        sm.bd1_s[j] = bd1[j];
        float4 a0 = reinterpret_cast<const float4*>(Wd2 + (size_t)j * 8)[0];
        float4 a1 = reinterpret_cast<const float4*>(Wd2 + (size_t)j * 8)[1];
        sm.wd2t_f[0][j] = a0.x; sm.wd2t_f[1][j] = a0.y;
        sm.wd2t_f[2][j] = a0.z; sm.wd2t_f[3][j] = a0.w;
        sm.wd2t_f[4][j] = a1.x; sm.wd2t_f[5][j] = a1.y;
        sm.wd2t_f[6][j] = a1.z; sm.wd2t_f[7][j] = a1.w;
    }
    if (tid < NN_) sm.m_s[tid] = mask[(size_t)b * NN_ + tid];
    if (tid < ZD) {
        float zf = z0[(size_t)b * ZD + tid];
        sm.z_ds[tid]  = (double)zf;
        sm.z_f[tid]   = zf;
        sm.bb2_d[tid] = (double)bb2[tid];
    }
    if (tid < 8) sm.bd2_d[tid] = (double)bd2[tid];

    // Wd1 z-block -> swizzled LDS
#pragma unroll
    for (int kk = 0; kk < 16; kk++) {
        const int k = q2 * 16 + kk;
        const float v = Wd1[(8 + k) * HID + j];
        reinterpret_cast<float*>(&sm.wd1z4[j][0])[4 * ((k >> 2) ^ (j & 15)) + (k & 3)] = v;
    }

    float wd1x[8];                       // Wd1 x-rows, column j (exact f32)
#pragma unroll
    for (int k = 0; k < 8; k++) wd1x[k] = Wd1[k * HID + j];

    __syncthreads();

    // ---------------- encoder (once, f64) ----------------
    if (tid < 256) {
        float we1r[16];
#pragma unroll
        for (int k = 0; k < 16; k++) we1r[k] = We1[k * HID + j];
        double be1_d = (double)be1[j];
        double msum = 0.0;
        for (int n = 0; n < NN_; n++) msum += (double)sm.m_s[n];
        msum = fmax(msum, 1.0);
        double pacc = 0.0;
        for (int n = 0; n < NN_; n++) {
            double pre = be1_d;
#pragma unroll
            for (int k = 0; k < 8; k++) pre = fma((double)sm.x_s[n][k], (double)we1r[k], pre);
#pragma unroll
            for (int k = 0; k < 8; k++) pre = fma((double)sm.y_s[n][k], (double)we1r[8 + k], pre);
            pacc += gelu_d(pre) * (double)sm.m_s[n];
        }
        sm.hb_ds[j] = pacc / msum;
    }
    __syncthreads();
    if (tid < 256) {
        int i = tid & 127, half = tid >> 7;
        double racc = 0.0;
        for (int jj = half * 128; jj < half * 128 + 128; jj++)
            racc = fma(sm.hb_ds[jj], (double)We2[jj * RD + i], racc);
        sm.scratch4[half][i] = racc;
    }
    __syncthreads();
    if (tid < RD) r_d[tid] = sm.scratch4[0][tid] + sm.scratch4[1][tid] + (double)be2[tid];
    __syncthreads();

    if (tid < 256) {                     // step-invariant drift-hidden -> LDS
        double hbr = (double)bb1[j];
        for (int k = 0; k < RD; k++)
            hbr = fma(r_d[k], (double)Wb1[(ZD + k) * HID + j], hbr);
        sm.hbt_s[j] = hbr;
        sm.wbt_s[j] = (double)Wb1[(ZD + RD) * HID + j];
    }
    __syncthreads();                     // r_d alias free after this

    const double dt  = 1.0 / (double)NSTEPS;
    const double nsc = sqrt(2.0 * 1.0 * dt);

    float* h_f   = reinterpret_cast<float*>(&sm.h_t[0][0]);    // f32 alias, stride PADD
    float* res_f = reinterpret_cast<float*>(&sm.res_r[0][0]);  // f32 alias (256 slots)
    float* pm_f  = reinterpret_cast<float*>(&sm.pmgz[0]);      // f32 alias (2048 slots)

    // ================= LOOP A: steps 0..SPLIT-1, pure f64 =================
    for (int s = 0; s < SPLIT; s++) {
        const double t = (double)s * dt;

        float nzf = 0.0f;
        if (tid < ZD) nzf = noise[((size_t)s * BB + b) * ZD + tid];

        // phase 1: A drift-hidden partials (f64) + zdot quarter-partials
        {
            const int kb = q2 * 16;
            const float* wb1p = Wb1 + kb * HID + j;
            double a0 = 0.0;
#pragma unroll 8
            for (int kk = 0; kk < 16; kk++)
                a0 = fma(sm.z_ds[kb + kk], (double)wb1p[kk * HID], a0);
            sm.scratch4[q2][j] = a0;

            double zq0 = 0.0, zq1 = 0.0;
#pragma unroll
            for (int q = q2 * 4; q < q2 * 4 + 4; q++) {
                float4 wv = sm.wd1z4[j][q ^ (j & 15)];
                const int k = q * 4;
                zq0 = fma(sm.z_ds[k],     (double)wv.x, zq0);
                zq1 = fma(sm.z_ds[k + 1], (double)wv.y, zq1);
                zq0 = fma(sm.z_ds[k + 2], (double)wv.z, zq0);
                zq1 = fma(sm.z_ds[k + 3], (double)wv.w, zq1);
            }
            sm.pmgz[q2 * 256 + j] = zq0 + zq1;
        }
        __syncthreads();
        // phase 2: drift hidden gelu (f64)
        if (tid < 256) {
            double hacc = sm.hbt_s[j] + t * sm.wbt_s[j]
                        + sm.scratch4[0][j] + sm.scratch4[1][j]
                        + sm.scratch4[2][j] + sm.scratch4[3][j];
            sm.hb_ds[j] = gelu_d(hacc);
        }
        __syncthreads();
        // drift out partials (f64)
        {
            const float* wb2p = Wb2 + (du_c * 16) * ZD + du_k;
            double acc = 0.0;
#pragma unroll 8
            for (int i = 0; i < 16; i++)
                acc = fma(sm.hb_ds[du_c * 16 + i], (double)wb2p[i * ZD], acc);
            sm.bp_d[du_c][du_k] = acc;
        }

        if (s > 0) {
            const double zpre = (double)sm.bd1_s[j]
                + ((sm.pmgz[j] + sm.pmgz[256 + j]) + (sm.pmgz[512 + j] + sm.pmgz[768 + j]));
            const int rb = q2 * 4;

            float gp_r0, gp_r1, gp_r2, gp_r3;
            double T0 = 0.0, T1 = 0.0, T2 = 0.0, T3 = 0.0;
            double T4 = 0.0, T5 = 0.0, T6 = 0.0, T7 = 0.0;

            for (int tile = 0; tile < NTILES; tile++) {
                const int xb = tile * NT + rb;
                {
                    const float4 xa = *reinterpret_cast<const float4*>(&sm.x_s[xb + 0][0]);
                    const float4 xxb = *reinterpret_cast<const float4*>(&sm.x_s[xb + 0][4]);
                    const float4 xc = *reinterpret_cast<const float4*>(&sm.x_s[xb + 1][0]);
                    const float4 xd = *reinterpret_cast<const float4*>(&sm.x_s[xb + 1][4]);
                    double p0 = zpre, p1 = zpre;
                    p0 = fma((double)xa.x, (double)wd1x[0], p0);
                    p0 = fma((double)xa.y, (double)wd1x[1], p0);
                    p0 = fma((double)xa.z, (double)wd1x[2], p0);
                    p0 = fma((double)xa.w, (double)wd1x[3], p0);
                    p0 = fma((double)xxb.x, (double)wd1x[4], p0);
                    p0 = fma((double)xxb.y, (double)wd1x[5], p0);
                    p0 = fma((double)xxb.z, (double)wd1x[6], p0);
                    p0 = fma((double)xxb.w, (double)wd1x[7], p0);
                    p1 = fma((double)xc.x, (double)wd1x[0], p1);
                    p1 = fma((double)xc.y, (double)wd1x[1], p1);
                    p1 = fma((double)xc.z, (double)wd1x[2], p1);
                    p1 = fma((double)xc.w, (double)wd1x[3], p1);
                    p1 = fma((double)xd.x, (double)wd1x[4], p1);
                    p1 = fma((double)xd.y, (double)wd1x[5], p1);
                    p1 = fma((double)xd.z, (double)wd1x[6], p1);
                    p1 = fma((double)xd.w, (double)wd1x[7], p1);
                    double h0, g0, h1, g1;
                    gelu_both_d(p0, h0, g0);
                    gelu_both_d(p1, h1, g1);
                    sm.h_t[rb + 0][j] = h0; gp_r0 = (float)g0;
                    sm.h_t[rb + 1][j] = h1; gp_r1 = (float)g1;
                }
                {
                    const float4 xa = *reinterpret_cast<const float4*>(&sm.x_s[xb + 2][0]);
                    const float4 xxb = *reinterpret_cast<const float4*>(&sm.x_s[xb + 2][4]);
                    const float4 xc = *reinterpret_cast<const float4*>(&sm.x_s[xb + 3][0]);
                    const float4 xd = *reinterpret_cast<const float4*>(&sm.x_s[xb + 3][4]);
                    double p0 = zpre, p1 = zpre;
                    p0 = fma((double)xa.x, (double)wd1x[0], p0);
                    p0 = fma((double)xa.y, (double)wd1x[1], p0);
                    p0 = fma((double)xa.z, (double)wd1x[2], p0);
                    p0 = fma((double)xa.w, (double)wd1x[3], p0);
                    p0 = fma((double)xxb.x, (double)wd1x[4], p0);
                    p0 = fma((double)xxb.y, (double)wd1x[5], p0);
                    p0 = fma((double)xxb.z, (double)wd1x[6], p0);
                    p0 = fma((double)xxb.w, (double)wd1x[7], p0);
                    p1 = fma((double)xc.x, (double)wd1x[0], p1);
                    p1 = fma((double)xc.y, (double)wd1x[1], p1);
                    p1 = fma((double)xc.z, (double)wd1x[2], p1);
                    p1 = fma((double)xc.w, (double)wd1x[3], p1);
                    p1 = fma((double)xd.x, (double)wd1x[4], p1);
                    p1 = fma((double)xd.y, (double)wd1x[5], p1);
                    p1 = fma((double)xd.z, (double)wd1x[6], p1);
                    p1 = fma((double)xd.w, (double)wd1x[7], p1);
                    double h0, g0, h1, g1;
                    gelu_both_d(p0, h0, g0);
                    gelu_both_d(p1, h1, g1);
                    sm.h_t[rb + 2][j] = h0; gp_r2 = (float)g0;
                    sm.h_t[rb + 3][j] = h1; gp_r3 = (float)g1;
                }
                __syncthreads();
                {
                    const int q = tid >> 7, pair = tid & 127;
                    const int nn = pair >> 3, yd = pair & 7;
                    const double2* hrow = reinterpret_cast<const double2*>(&sm.h_t[nn][q * 32]);
                    const float2*  wrow = reinterpret_cast<const float2*>(&sm.wd2t_f[yd][q * 32]);
                    double a0 = 0.0, a1 = 0.0;
#pragma unroll 8
                    for (int i = 0; i < 16; i++) {
                        double2 hv = hrow[i];
                        float2  wv = wrow[i];
                        a0 = fma(hv.x, (double)wv.x, a0);
                        a1 = fma(hv.y, (double)wv.y, a1);
                    }
                    sm.pmgz[q * 128 + pair] = a0 + a1;
                }
                __syncthreads();
                if (tid < 128) {
                    const int nn = tid >> 3, yd = tid & 7;
                    double mu = sm.bd2_d[yd];
#pragma unroll
                    for (int q = 0; q < 8; q++) mu += sm.pmgz[q * 128 + tid];
                    sm.res_r[nn][yd] = 4.0 * t * (mu - (double)sm.y_s[tile * NT + nn][yd])
                                               * (double)sm.m_s[tile * NT + nn];
                }
                __syncthreads();
                {
                    const double2* rr0 = reinterpret_cast<const double2*>(&sm.res_r[rb + 0][0]);
                    const double2* rr1 = reinterpret_cast<const double2*>(&sm.res_r[rb + 1][0]);
                    const double2* rr2 = reinterpret_cast<const double2*>(&sm.res_r[rb + 2][0]);
                    const double2* rr3 = reinterpret_cast<const double2*>(&sm.res_r[rb + 3][0]);
                    double2 a0, a1, a2, a3;
                    double g;
                    g = (double)gp_r0;
                    a0 = rr0[0]; a1 = rr0[1]; a2 = rr0[2]; a3 = rr0[3];
                    T0 = fma(a0.x, g, T0); T1 = fma(a0.y, g, T1);
                    T2 = fma(a1.x, g, T2); T3 = fma(a1.y, g, T3);
                    T4 = fma(a2.x, g, T4); T5 = fma(a2.y, g, T5);
                    T6 = fma(a3.x, g, T6); T7 = fma(a3.y, g, T7);
                    g = (double)gp_r1;
                    a0 = rr1[0]; a1 = rr1[1]; a2 = rr1[2]; a3 = rr1[3];
                    T0 = fma(a0.x, g, T0); T1 = fma(a0.y, g, T1);
                    T2 = fma(a1.x, g, T2); T3 = fma(a1.y, g, T3);
                    T4 = fma(a2.x, g, T4); T5 = fma(a2.y, g, T5);
                    T6 = fma(a3.x, g, T6); T7 = fma(a3.y, g, T7);
                    g = (double)gp_r2;
                    a0 = rr2[0]; a1 = rr2[1]; a2 = rr2[2]; a3 = rr2[3];
                    T0 = fma(a0.x, g, T0); T1 = fma(a0.y, g, T1);
                    T2 = fma(a1.x, g, T2); T3 = fma(a1.y, g, T3);
                    T4 = fma(a2.x, g, T4); T5 = fma(a2.y, g, T5);
                    T6 = fma(a3.x, g, T6); T7 = fma(a3.y, g, T7);
                    g = (double)gp_r3;
                    a0 = rr3[0]; a1 = rr3[1]; a2 = rr3[2]; a3 = rr3[3];
                    T0 = fma(a0.x, g, T0); T1 = fma(a0.y, g, T1);
                    T2 = fma(a1.x, g, T2); T3 = fma(a1.y, g, T3);
                    T4 = fma(a2.x, g, T4); T5 = fma(a2.y, g, T5);
                    T6 = fma(a3.x, g, T6); T7 = fma(a3.y, g, T7);
                }
            }
            {
                double S = T0 * (double)sm.wd2t_f[0][j];
                S = fma(T1, (double)sm.wd2t_f[1][j], S);
                S = fma(T2, (double)sm.wd2t_f[2][j], S);
                S = fma(T3, (double)sm.wd2t_f[3][j], S);
                S = fma(T4, (double)sm.wd2t_f[4][j], S);
                S = fma(T5, (double)sm.wd2t_f[5][j], S);
                S = fma(T6, (double)sm.wd2t_f[6][j], S);
                S = fma(T7, (double)sm.wd2t_f[7][j], S);
                sm.scratch4[q2][j] = S;
            }
            __syncthreads();
            // gradient matvec (f64)
            {
                const int k = du_k, c = du_c;
                const int qk = k >> 2, ck = k & 3;
                double acc = 0.0;
#pragma unroll 8
                for (int i = 0; i < 16; i++) {
                    const int jj = c * 16 + i;
                    const float w = reinterpret_cast<const float*>(&sm.wd1z4[jj][0])
                                        [4 * (qk ^ (jj & 15)) + ck];
                    const double sv = sm.scratch4[0][jj] + sm.scratch4[1][jj]
                                    + sm.scratch4[2][jj] + sm.scratch4[3][jj];
                    acc = fma(sv, (double)w, acc);
                }
                sm.pmgz[c * 64 + k] = acc;
            }
            __syncthreads();
        } else {
            __syncthreads();   // s==0: make bp_d visible to the update
        }

        // z update
        if (tid < ZD) {
            double gsum = sm.z_ds[tid];
            if (s > 0) {
#pragma unroll
                for (int c = 0; c < 16; c++) gsum += sm.pmgz[c * 64 + tid];
            }
            gsum = fmin(fmax(gsum, -100.0), 100.0);
            double bdr = sm.bb2_d[tid];
#pragma unroll
            for (int c = 0; c < 16; c++) bdr += sm.bp_d[c][tid];
            double znew = sm.z_ds[tid] + (bdr - gsum) * dt + nsc * (double)nzf;
            sm.z_ds[tid] = znew;
            sm.z_f[tid]  = (float)znew;
        }
        __syncthreads();
    }

    // ========== LOOP B: steps SPLIT..NSTEPS-1, f32, 32-row tiles ==========
    for (int s = SPLIT; s < NSTEPS; s++) {
        const double t = (double)s * dt;

        float nzf = 0.0f;
        if (tid < ZD) nzf = noise[((size_t)s * BB + b) * ZD + tid];

        // phase 1: A drift-hidden partials (f32) + zdot quarter-partials (f64)
        {
            const int kb = q2 * 16;
            const float* wb1p = Wb1 + kb * HID + j;
            float a0f = 0.0f;
#pragma unroll 8
            for (int kk = 0; kk < 16; kk++)
                a0f = fmaf(sm.z_f[kb + kk], wb1p[kk * HID], a0f);
            sm.scratch4[q2][j] = (double)a0f;

            double zq0 = 0.0, zq1 = 0.0;
#pragma unroll
            for (int q = q2 * 4; q < q2 * 4 + 4; q++) {
                float4 wv = sm.wd1z4[j][q ^ (j & 15)];
                const int k = q * 4;
                zq0 = fma(sm.z_ds[k],     (double)wv.x, zq0);
                zq1 = fma(sm.z_ds[k + 1], (double)wv.y, zq1);
                zq0 = fma(sm.z_ds[k + 2], (double)wv.z, zq0);
                zq1 = fma(sm.z_ds[k + 3], (double)wv.w, zq1);
            }
            sm.pmgz[q2 * 256 + j] = zq0 + zq1;
        }
        __syncthreads();
        // phase 2: drift hidden gelu (f32)
        if (tid < 256) {
            double hacc = sm.hbt_s[j] + t * sm.wbt_s[j]
                        + sm.scratch4[0][j] + sm.scratch4[1][j]
                        + sm.scratch4[2][j] + sm.scratch4[3][j];
            sm.hb_f[j] = gelu_f32((float)hacc);
        }
        __syncthreads();
        // drift out partials (f32)
        {
            const float* wb2p = Wb2 + (du_c * 16) * ZD + du_k;
            float accf = 0.0f;
#pragma unroll 8
            for (int i = 0; i < 16; i++)
                accf = fmaf(sm.hb_f[du_c * 16 + i], wb2p[i * ZD], accf);
            sm.bp_d[du_c][du_k] = (double)accf;
        }

        const double zpre = (double)sm.bd1_s[j]
            + ((sm.pmgz[j] + sm.pmgz[256 + j]) + (sm.pmgz[512 + j] + sm.pmgz[768 + j]));
        const float zpre_f = (float)zpre;
        const int rb2 = q2 * 8;          // 8 rows/thread within a 32-row tile

        float gpA, gpB, gpC, gpD, gpE, gpF2, gpG, gpH;
        float T0 = 0.f, T1 = 0.f, T2 = 0.f, T3 = 0.f;
        float T4 = 0.f, T5 = 0.f, T6 = 0.f, T7 = 0.f;

        for (int tile = 0; tile < 4; tile++) {
            const int xb = tile * 32 + rb2;
            // F: 8 rows as 4 ILP pairs
#define FPAIR(RO, GA, GB) { \
            const float4 xa = *reinterpret_cast<const float4*>(&sm.x_s[xb + (RO)][0]); \
            const float4 xbv = *reinterpret_cast<const float4*>(&sm.x_s[xb + (RO)][4]); \
            const float4 xc = *reinterpret_cast<const float4*>(&sm.x_s[xb + (RO) + 1][0]); \
            const float4 xdv = *reinterpret_cast<const float4*>(&sm.x_s[xb + (RO) + 1][4]); \
            float p0 = zpre_f, p1 = zpre_f; \
            p0 = fmaf(xa.x, wd1x[0], p0);  p0 = fmaf(xa.y, wd1x[1], p0); \
            p0 = fmaf(xa.z, wd1x[2], p0);  p0 = fmaf(xa.w, wd1x[3], p0); \
            p0 = fmaf(xbv.x, wd1x[4], p0); p0 = fmaf(xbv.y, wd1x[5], p0); \
            p0 = fmaf(xbv.z, wd1x[6], p0); p0 = fmaf(xbv.w, wd1x[7], p0); \
            p1 = fmaf(xc.x, wd1x[0], p1);  p1 = fmaf(xc.y, wd1x[1], p1); \
            p1 = fmaf(xc.z, wd1x[2], p1);  p1 = fmaf(xc.w, wd1x[3], p1); \
            p1 = fmaf(xdv.x, wd1x[4], p1); p1 = fmaf(xdv.y, wd1x[5], p1); \
            p1 = fmaf(xdv.z, wd1x[6], p1); p1 = fmaf(xdv.w, wd1x[7], p1); \
            float h0, g0, h1, g1; \
            gelu_both_f(p0, h0, g0); \
            gelu_both_f(p1, h1, g1); \
            h_f[(rb2 + (RO)) * PADD + j]     = h0; \
            h_f[(rb2 + (RO) + 1) * PADD + j] = h1; \
            GA = g0; GB = g1; }
            FPAIR(0, gpA, gpB)
            FPAIR(2, gpC, gpD)
            FPAIR(4, gpE, gpF2)
            FPAIR(6, gpG, gpH)
#undef FPAIR
            __syncthreads();
            // M: 2048 slots (32 rows x 8 yd x 8 octants), 2 per thread.
#pragma unroll
            for (int it = 0; it < 2; it++) {
                const int slot = tid + it * 1024;
                const int q = slot >> 8, pair = slot & 255;
                const int nn = pair >> 3, yd = pair & 7;
                const float2* hrow =
                    reinterpret_cast<const float2*>(h_f + nn * PADD) + q * 16;
                const float2* wrow =
                    reinterpret_cast<const float2*>(&sm.wd2t_f[yd][0]) + q * 16;
                float a0 = 0.f, a1 = 0.f;
#pragma unroll 8
                for (int i = 0; i < 16; i++) {
                    float2 hv = hrow[i];
                    float2 wv = wrow[i];
                    a0 = fmaf(hv.x, wv.x, a0);
                    a1 = fmaf(hv.y, wv.y, a1);
                }
                pm_f[slot] = a0 + a1;
            }
            __syncthreads();
            // R: 256 outputs (32 rows x 8 yd)
            if (tid < 256) {
                const int nn = tid >> 3, yd = tid & 7;
                double mu = sm.bd2_d[yd];
#pragma unroll
                for (int q = 0; q < 8; q++) mu += (double)pm_f[q * 256 + tid];
                const int row = tile * 32 + nn;
                res_f[tid] = (float)(4.0 * t * (mu - (double)sm.y_s[row][yd])
                                             * (double)sm.m_s[row]);
            }
            __syncthreads();
            // B: 8 rows/thread (flows into next F; disjoint buffers)
#define BROW(RO, G) { \
            const float2* rr = reinterpret_cast<const float2*>(res_f + (rb2 + (RO)) * 8); \
            float2 a0 = rr[0], a1 = rr[1], a2 = rr[2], a3 = rr[3]; \
            T0 = fmaf(a0.x, (G), T0); T1 = fmaf(a0.y, (G), T1); \
            T2 = fmaf(a1.x, (G), T2); T3 = fmaf(a1.y, (G), T3); \
            T4 = fmaf(a2.x, (G), T4); T5 = fmaf(a2.y, (G), T5); \
            T6 = fmaf(a3.x, (G), T6); T7 = fmaf(a3.y, (G), T7); }
            BROW(0, gpA) BROW(1, gpB) BROW(2, gpC) BROW(3, gpD)
            BROW(4, gpE) BROW(5, gpF2) BROW(6, gpG) BROW(7, gpH)
#undef BROW
        }
        {
            float Sf = T0 * sm.wd2t_f[0][j];
            Sf = fmaf(T1, sm.wd2t_f[1][j], Sf);
            Sf = fmaf(T2, sm.wd2t_f[2][j], Sf);
            Sf = fmaf(T3, sm.wd2t_f[3][j], Sf);
            Sf = fmaf(T4, sm.wd2t_f[4][j], Sf);
            Sf = fmaf(T5, sm.wd2t_f[5][j], Sf);
            Sf = fmaf(T6, sm.wd2t_f[6][j], Sf);
            Sf = fmaf(T7, sm.wd2t_f[7][j], Sf);
            sm.scratch4[q2][j] = (double)Sf;
        }
        __syncthreads();

        // gradient matvec (f64)
        {
            const int k = du_k, c = du_c;
            const int qk = k >> 2, ck = k & 3;
            double acc = 0.0;
#pragma unroll 8
            for (int i = 0; i < 16; i++) {
                const int jj = c * 16 + i;
                const float w = reinterpret_cast<const float*>(&sm.wd1z4[jj][0])
                                    [4 * (qk ^ (jj & 15)) + ck];
                const double sv = sm.scratch4[0][jj] + sm.scratch4[1][jj]
                                + sm.scratch4[2][jj] + sm.scratch4[3][jj];
                acc = fma(sv, (double)w, acc);
            }
            sm.pmgz[c * 64 + k] = acc;
        }
        __syncthreads();
        // z update
        if (tid < ZD) {
            double gsum = sm.z_ds[tid];
#pragma unroll
            for (int c = 0; c < 16; c++) gsum += sm.pmgz[c * 64 + tid];
            gsum = fmin(fmax(gsum, -100.0), 100.0);
            double bdr = sm.bb2_d[tid];
#pragma unroll
            for (int c = 0; c < 16; c++) bdr += sm.bp_d[c][tid];
            double znew = sm.z_ds[tid] + (bdr - gsum) * dt + nsc * (double)nzf;
            sm.z_ds[tid] = znew;
            sm.z_f[tid]  = (float)znew;
        }
        __syncthreads();
    }

    if (tid < ZD) out[(size_t)b * ZD + tid] = (float)sm.z_ds[tid];
}

extern "C" void kernel_launch(void* const* d_in, const int* in_sizes, int n_in,
                              void* d_out, int out_size, void* d_ws, size_t ws_size,
                              hipStream_t stream) {
    const float* x_ctx = (const float*)d_in[0];
    const float* y_ctx = (const float*)d_in[1];
    const float* maskp = (const float*)d_in[2];
    const float* z0    = (const float*)d_in[3];
    const float* noise = (const float*)d_in[4];
    const float* We1   = (const float*)d_in[5];
    const float* be1   = (const float*)d_in[6];
    const float* We2   = (const float*)d_in[7];
    const float* be2   = (const float*)d_in[8];
    const float* Wd1   = (const float*)d_in[9];
    const float* bd1   = (const float*)d_in[10];
    const float* Wd2   = (const float*)d_in[11];
    const float* bd2   = (const float*)d_in[12];
    const float* Wb1   = (const float*)d_in[13];
    const float* bb1   = (const float*)d_in[14];
    const float* Wb2   = (const float*)d_in[15];
    const float* bb2   = (const float*)d_in[16];
    float* out = (float*)d_out;

    (void)hipFuncSetAttribute((const void*)nets_sampler_kernel,
                              hipFuncAttributeMaxDynamicSharedMemorySize,
                              (int)sizeof(Smem));

    nets_sampler_kernel<<<BB, TPB, sizeof(Smem), stream>>>(
        x_ctx, y_ctx, maskp, z0, noise,
        We1, be1, We2, be2, Wd1, bd1, Wd2, bd2, Wb1, bb1, Wb2, bb2, out);
}